// Round 4
// baseline (17969.049 us; speedup 1.0000x reference)
//
#include <hip/hip_runtime.h>
#include <hip/hip_bf16.h>

#define QD 1024
#define AD 26
#define BD 128
#define LD 1024
#define NWG 64

typedef short bf16x8 __attribute__((ext_vector_type(8)));
typedef float f32x4 __attribute__((ext_vector_type(4)));

static __device__ __forceinline__ unsigned short f2bf(float f) {
    __hip_bfloat16 h = __float2bfloat16(f);
    return *reinterpret_cast<unsigned short*>(&h);
}

// Device-coherent (agent-scope, relaxed) 16B alpha load as two 8B atomic loads.
// Emits global_load_dwordx2 with sc bits: bypasses stale per-CU L1 / per-XCD L2,
// served by the shared LLC. No fences, pipelined by the normal waitcnt machinery.
static __device__ __forceinline__ bf16x8 load_a16(const unsigned short* p) {
    unsigned long long lo = __hip_atomic_load((const unsigned long long*)p,
                                              __ATOMIC_RELAXED, __HIP_MEMORY_SCOPE_AGENT);
    unsigned long long hi = __hip_atomic_load((const unsigned long long*)(p + 4),
                                              __ATOMIC_RELAXED, __HIP_MEMORY_SCOPE_AGENT);
    union { unsigned long long q[2]; bf16x8 v; } u;
    u.q[0] = lo; u.q[1] = hi;
    return u.v;
}

// Device-coherent 8B alpha store (write-through past L2; visible once vmcnt retires).
static __device__ __forceinline__ void store_a8(unsigned short* p, ushort4 v) {
    union { ushort4 s; unsigned long long q; } u; u.s = v;
    __hip_atomic_store((unsigned long long*)p, u.q,
                       __ATOMIC_RELAXED, __HIP_MEMORY_SCOPE_AGENT);
}

// Row-softmax of trans_logits [1024,1024] -> bf16 packed as A-fragments of T^T.
// A-frag layout (16x16x32): A[m = lane&15][k = quad*8 + j].
// For T element [i=q_in][c=q_out]: mt=c>>4, col=c&15, kt=i>>5, quad=(i>>3)&3, j=i&7.
__global__ void softmax_pack_T(const float* __restrict__ tl, unsigned short* __restrict__ tf) {
    const int i = blockIdx.x;      // q_in
    const int tid = threadIdx.x;   // 256
    __shared__ float red[256];
    float v[4];
    float m = -1e30f;
    for (int c = 0; c < 4; ++c) { v[c] = tl[i * QD + tid + 256 * c]; m = fmaxf(m, v[c]); }
    red[tid] = m; __syncthreads();
    for (int s = 128; s > 0; s >>= 1) { if (tid < s) red[tid] = fmaxf(red[tid], red[tid + s]); __syncthreads(); }
    m = red[0]; __syncthreads();
    float sum = 0.f;
    for (int c = 0; c < 4; ++c) { v[c] = expf(v[c] - m); sum += v[c]; }
    red[tid] = sum; __syncthreads();
    for (int s = 128; s > 0; s >>= 1) { if (tid < s) red[tid] += red[tid + s]; __syncthreads(); }
    const float inv = 1.0f / red[0];
    const int kt = i >> 5, quad = (i >> 3) & 3, j = i & 7;
    for (int c = 0; c < 4; ++c) {
        const int q = tid + 256 * c;
        const int mt = q >> 4, col = q & 15;
        tf[(size_t)((mt * 32 + kt) * 64 + quad * 16 + col) * 8 + j] = f2bf(v[c] * inv);
    }
}

// Row-softmax of emis_logits [1024,26] -> bf16 A-fragments (M=q, K=a padded to 32).
__global__ void softmax_pack_B(const float* __restrict__ el, unsigned short* __restrict__ bmf) {
    const int q = blockIdx.x * blockDim.x + threadIdx.x;
    if (q >= QD) return;
    float v[AD];
    float m = -1e30f;
    for (int a = 0; a < AD; ++a) { v[a] = el[q * AD + a]; m = fmaxf(m, v[a]); }
    float sum = 0.f;
    for (int a = 0; a < AD; ++a) { v[a] = expf(v[a] - m); sum += v[a]; }
    const float inv = 1.0f / sum;
    const int mt = q >> 4, col = q & 15;
    for (int a = 0; a < 32; ++a) {
        const float val = (a < AD) ? v[a] * inv : 0.f;
        bmf[(size_t)(mt * 64 + (a >> 3) * 16 + col) * 8 + (a & 7)] = f2bf(val);
    }
}

__global__ void softmax_pi(const float* __restrict__ il, float* __restrict__ pi) {
    const int tid = threadIdx.x;   // 1024
    __shared__ float red[1024];
    const float v = il[tid];
    red[tid] = v; __syncthreads();
    for (int s = 512; s > 0; s >>= 1) { if (tid < s) red[tid] = fmaxf(red[tid], red[tid + s]); __syncthreads(); }
    const float m = red[0]; __syncthreads();
    const float e = expf(v - m);
    red[tid] = e; __syncthreads();
    for (int s = 512; s > 0; s >>= 1) { if (tid < s) red[tid] += red[tid + s]; __syncthreads(); }
    pi[tid] = e / red[0];
}

// Cooperative scan: 64 WGs x 256 threads. WG = (qs: 32 q_out) x (bg: 64 batches).
// T^T slice [32 q_out x 1024 q_in] = 64 KB LDS, resident all 1024 steps.
// Consumer-side normalization via ones-A MFMA column sums (c_t identical across WGs).
// Grid sync: scoped write-through alpha stores -> syncthreads (drains vmcnt) ->
// relaxed agent flag add by tid0 -> [hide: stage inputs(t+1) + emission MFMA] ->
// relaxed agent spin. NO release/acquire fences => no buffer_wbl2/buffer_inv =>
// L2 stays warm. Data coherence comes from the sc-scoped data ops themselves.
__launch_bounds__(256)
__global__ void hmm_scan(const float* __restrict__ inputs,
                         const unsigned short* __restrict__ tf,
                         const unsigned short* __restrict__ bmf,
                         const float* __restrict__ pi,
                         unsigned short* __restrict__ abuf,   // 2 x [BD][QD] bf16
                         unsigned int* __restrict__ bar,      // zeroed
                         float* __restrict__ out) {
    __shared__ unsigned short ts[2 * 32 * 64 * 8];   // 64 KB T^T A-frags
    __shared__ unsigned short int_t[64 * 32];        // inputs[b][a] bf16, pad 32
    __shared__ float cbuf[64];

    const int tid   = threadIdx.x;
    const int wave  = tid >> 6;
    const int lane  = tid & 63;
    const int quad  = lane >> 4;
    const int col   = lane & 15;
    const int mtl   = wave & 1;
    const int bhalf = wave >> 1;
    const int qs    = (int)blockIdx.x >> 1;
    const int bg    = (int)blockIdx.x & 1;
    const int bbase = bg * 64 + bhalf * 32;
    const int qrow  = qs * 32 + mtl * 16 + quad * 4;

    // T^T slice into LDS (contiguous 64 KB).
    {
        const float4* src = (const float4*)(tf + (size_t)(qs * 2) * 32 * 64 * 8);
        float4* dst = (float4*)ts;
        for (int i = tid; i < 4096; i += 256) dst[i] = src[i];
    }
    const bf16x8 bmA = *(const bf16x8*)&bmf[(size_t)((qs * 2 + mtl) * 64 + lane) * 8];
    float pr[4];
    #pragma unroll
    for (int r = 0; r < 4; ++r) pr[r] = pi[qrow + r];

    bf16x8 ones;
    #pragma unroll
    for (int i = 0; i < 8; ++i) ones[i] = (short)0x3F80;

    const f32x4 fz = {0.f, 0.f, 0.f, 0.f};
    float ll = 0.f;

    // Prologue: stage inputs(0) and compute emissions(0).
    for (int idx = tid; idx < 64 * 32; idx += 256) {
        const int row = idx >> 5, a = idx & 31;
        const float v = (a < AD) ? inputs[((size_t)(bg * 64 + row) * LD) * AD + a] : 0.f;
        int_t[idx] = f2bf(v);
    }
    __syncthreads();
    f32x4 e0, e1, acc0 = fz, acc1 = fz, on0 = fz, on1 = fz;
    {
        bf16x8 x0 = *(const bf16x8*)&int_t[(bhalf * 32 + col) * 32 + quad * 8];
        bf16x8 x1 = *(const bf16x8*)&int_t[(bhalf * 32 + 16 + col) * 32 + quad * 8];
        e0 = __builtin_amdgcn_mfma_f32_16x16x32_bf16(bmA, x0, fz, 0, 0, 0);
        e1 = __builtin_amdgcn_mfma_f32_16x16x32_bf16(bmA, x1, fz, 0, 0, 0);
    }

    for (int t = 0; t < LD; ++t) {
        // alpha_t for this tile (acc/on were computed from alpha(t-1) last iteration).
        float v0[4], v1[4];
        if (t == 0) {
            #pragma unroll
            for (int r = 0; r < 4; ++r) { v0[r] = pr[r] * e0[r]; v1[r] = pr[r] * e1[r]; }
        } else {
            const float i0 = 1.f / on0[0], i1 = 1.f / on1[0];
            #pragma unroll
            for (int r = 0; r < 4; ++r) { v0[r] = acc0[r] * e0[r] * i0; v1[r] = acc1[r] * e1[r] * i1; }
        }
        unsigned short* aw = abuf + (size_t)(t & 1) * BD * QD;
        ushort4 s0, s1;
        s0.x = f2bf(v0[0]); s0.y = f2bf(v0[1]); s0.z = f2bf(v0[2]); s0.w = f2bf(v0[3]);
        s1.x = f2bf(v1[0]); s1.y = f2bf(v1[1]); s1.z = f2bf(v1[2]); s1.w = f2bf(v1[3]);
        store_a8(&aw[(size_t)(bbase + col) * QD + qrow], s0);
        store_a8(&aw[(size_t)(bbase + 16 + col) * QD + qrow], s1);

        if (t > 0 && mtl == 0 && quad == 0) {
            cbuf[bhalf * 32 + col] = on0[0];
            cbuf[bhalf * 32 + 16 + col] = on1[0];
        }
        asm volatile("s_waitcnt vmcnt(0)" ::: "memory");  // per-wave store drain
        __syncthreads();                                  // all waves drained; cbuf visible
        if (tid == 0)
            __hip_atomic_fetch_add(bar, 1u, __ATOMIC_RELAXED, __HIP_MEMORY_SCOPE_AGENT);
        if (t > 0 && tid < 64) ll += logf(cbuf[tid]);

        if (t + 1 < LD) {
            // Hidden behind other WGs' arrival: stage inputs(t+1) + emissions(t+1).
            for (int idx = tid; idx < 64 * 32; idx += 256) {
                const int row = idx >> 5, a = idx & 31;
                const float v = (a < AD)
                    ? inputs[((size_t)(bg * 64 + row) * LD + (t + 1)) * AD + a] : 0.f;
                int_t[idx] = f2bf(v);
            }
            __syncthreads();
            bf16x8 x0 = *(const bf16x8*)&int_t[(bhalf * 32 + col) * 32 + quad * 8];
            bf16x8 x1 = *(const bf16x8*)&int_t[(bhalf * 32 + 16 + col) * 32 + quad * 8];
            e0 = __builtin_amdgcn_mfma_f32_16x16x32_bf16(bmA, x0, fz, 0, 0, 0);
            e1 = __builtin_amdgcn_mfma_f32_16x16x32_bf16(bmA, x1, fz, 0, 0, 0);

            if (tid == 0) {
                const unsigned target = (unsigned)(t + 1) * NWG;
                while (__hip_atomic_load(bar, __ATOMIC_RELAXED, __HIP_MEMORY_SCOPE_AGENT) < target) {}
            }
            __syncthreads();

            // Consume alpha(t): scoped loads from LLC + MFMA chains -> acc/on for t+1.
            acc0 = fz; acc1 = fz; on0 = fz; on1 = fz;
            const unsigned short* ab = abuf + (size_t)(t & 1) * BD * QD;
            const unsigned short* arow0 = ab + (size_t)(bbase + col) * QD + quad * 8;
            const unsigned short* arow1 = ab + (size_t)(bbase + 16 + col) * QD + quad * 8;
            #pragma unroll 8
            for (int kt = 0; kt < 32; ++kt) {
                bf16x8 af = *(const bf16x8*)&ts[(size_t)((mtl * 32 + kt) * 64 + lane) * 8];
                bf16x8 b0 = load_a16(&arow0[(size_t)kt * 32]);
                bf16x8 b1 = load_a16(&arow1[(size_t)kt * 32]);
                acc0 = __builtin_amdgcn_mfma_f32_16x16x32_bf16(af, b0, acc0, 0, 0, 0);
                on0  = __builtin_amdgcn_mfma_f32_16x16x32_bf16(ones, b0, on0, 0, 0, 0);
                acc1 = __builtin_amdgcn_mfma_f32_16x16x32_bf16(af, b1, acc1, 0, 0, 0);
                on1  = __builtin_amdgcn_mfma_f32_16x16x32_bf16(ones, b1, on1, 0, 0, 0);
            }
        }
    }

    // Final normalizer c_{L-1}: only qs==0 WGs need it.
    if (qs == 0) {
        if (tid == 0) {
            while (__hip_atomic_load(bar, __ATOMIC_RELAXED, __HIP_MEMORY_SCOPE_AGENT)
                   < (unsigned)LD * NWG) {}
        }
        __syncthreads();
        const unsigned short* ab = abuf + (size_t)((LD - 1) & 1) * BD * QD;
        const unsigned short* arow0 = ab + (size_t)(bbase + col) * QD + quad * 8;
        const unsigned short* arow1 = ab + (size_t)(bbase + 16 + col) * QD + quad * 8;
        f32x4 f0 = fz, f1 = fz;
        #pragma unroll 8
        for (int kt = 0; kt < 32; ++kt) {
            bf16x8 b0 = load_a16(&arow0[(size_t)kt * 32]);
            bf16x8 b1 = load_a16(&arow1[(size_t)kt * 32]);
            f0 = __builtin_amdgcn_mfma_f32_16x16x32_bf16(ones, b0, f0, 0, 0, 0);
            f1 = __builtin_amdgcn_mfma_f32_16x16x32_bf16(ones, b1, f1, 0, 0, 0);
        }
        if (mtl == 0 && quad == 0) {
            cbuf[bhalf * 32 + col] = f0[0];
            cbuf[bhalf * 32 + 16 + col] = f1[0];
        }
        __syncthreads();
        if (tid < 64) out[bg * 64 + tid] = ll + logf(cbuf[tid]);
    }
}

extern "C" void kernel_launch(void* const* d_in, const int* in_sizes, int n_in,
                              void* d_out, int out_size, void* d_ws, size_t ws_size,
                              hipStream_t stream) {
    const float* inputs       = (const float*)d_in[0];
    const float* init_logits  = (const float*)d_in[1];
    const float* trans_logits = (const float*)d_in[2];
    const float* emis_logits  = (const float*)d_in[3];
    float* out = (float*)d_out;

    unsigned short* tf  = (unsigned short*)d_ws;                 // 2 MB
    unsigned short* bmf = tf + (size_t)QD * QD;                  // 64 KB
    float* pi           = (float*)(bmf + (size_t)QD * 32);       // 4 KB
    unsigned short* ab  = (unsigned short*)(pi + QD);            // 512 KB
    unsigned int* bar   = (unsigned int*)(ab + (size_t)2 * BD * QD);

    hipMemsetAsync(bar, 0, sizeof(unsigned int), stream);

    softmax_pack_T<<<1024, 256, 0, stream>>>(trans_logits, tf);
    softmax_pack_B<<<4, 256, 0, stream>>>(emis_logits, bmf);
    softmax_pi<<<1, 1024, 0, stream>>>(init_logits, pi);

    void* args[] = {(void*)&inputs, (void*)&tf, (void*)&bmf, (void*)&pi,
                    (void*)&ab, (void*)&bar, (void*)&out};
    hipLaunchCooperativeKernel((const void*)hmm_scan, dim3(NWG), dim3(256),
                               args, 0, stream);
}

// Round 5
// 11599.627 us; speedup vs baseline: 1.5491x; 1.5491x over previous
//
#include <hip/hip_runtime.h>
#include <hip/hip_bf16.h>

#define QD 1024
#define AD 26
#define BD 128
#define LD 1024
#define NWG 128   // 32 q-slices x 4 batch-domains

typedef short bf16x8 __attribute__((ext_vector_type(8)));
typedef float f32x4 __attribute__((ext_vector_type(4)));

static __device__ __forceinline__ unsigned short f2bf(float f) {
    __hip_bfloat16 h = __float2bfloat16(f);
    return *reinterpret_cast<unsigned short*>(&h);
}

// Agent-scope relaxed 16B load as two 8B atomic loads (bypass stale L1/L2, LLC-served).
static __device__ __forceinline__ bf16x8 load_a16(const unsigned short* p) {
    unsigned long long lo = __hip_atomic_load((const unsigned long long*)p,
                                              __ATOMIC_RELAXED, __HIP_MEMORY_SCOPE_AGENT);
    unsigned long long hi = __hip_atomic_load((const unsigned long long*)(p + 4),
                                              __ATOMIC_RELAXED, __HIP_MEMORY_SCOPE_AGENT);
    union { unsigned long long q[2]; bf16x8 v; } u;
    u.q[0] = lo; u.q[1] = hi;
    return u.v;
}

// Agent-scope relaxed 8B store (write-through past per-XCD L2; visible once vmcnt retires).
static __device__ __forceinline__ void store_a8(unsigned short* p, ushort4 v) {
    union { ushort4 s; unsigned long long q; } u; u.s = v;
    __hip_atomic_store((unsigned long long*)p, u.q,
                       __ATOMIC_RELAXED, __HIP_MEMORY_SCOPE_AGENT);
}

// Row-softmax of trans_logits [1024,1024] -> bf16 packed as A-fragments of T^T.
// A-frag layout (16x16x32): A[m = lane&15][k = quad*8 + j].
__global__ void softmax_pack_T(const float* __restrict__ tl, unsigned short* __restrict__ tf) {
    const int i = blockIdx.x;      // q_in
    const int tid = threadIdx.x;   // 256
    __shared__ float red[256];
    float v[4];
    float m = -1e30f;
    for (int c = 0; c < 4; ++c) { v[c] = tl[i * QD + tid + 256 * c]; m = fmaxf(m, v[c]); }
    red[tid] = m; __syncthreads();
    for (int s = 128; s > 0; s >>= 1) { if (tid < s) red[tid] = fmaxf(red[tid], red[tid + s]); __syncthreads(); }
    m = red[0]; __syncthreads();
    float sum = 0.f;
    for (int c = 0; c < 4; ++c) { v[c] = expf(v[c] - m); sum += v[c]; }
    red[tid] = sum; __syncthreads();
    for (int s = 128; s > 0; s >>= 1) { if (tid < s) red[tid] += red[tid + s]; __syncthreads(); }
    const float inv = 1.0f / red[0];
    const int kt = i >> 5, quad = (i >> 3) & 3, j = i & 7;
    for (int c = 0; c < 4; ++c) {
        const int q = tid + 256 * c;
        const int mt = q >> 4, col = q & 15;
        tf[(size_t)((mt * 32 + kt) * 64 + quad * 16 + col) * 8 + j] = f2bf(v[c] * inv);
    }
}

// Row-softmax of emis_logits [1024,26] -> bf16 A-fragments (M=q, K=a padded to 32).
__global__ void softmax_pack_B(const float* __restrict__ el, unsigned short* __restrict__ bmf) {
    const int q = blockIdx.x * blockDim.x + threadIdx.x;
    if (q >= QD) return;
    float v[AD];
    float m = -1e30f;
    for (int a = 0; a < AD; ++a) { v[a] = el[q * AD + a]; m = fmaxf(m, v[a]); }
    float sum = 0.f;
    for (int a = 0; a < AD; ++a) { v[a] = expf(v[a] - m); sum += v[a]; }
    const float inv = 1.0f / sum;
    const int mt = q >> 4, col = q & 15;
    for (int a = 0; a < 32; ++a) {
        const float val = (a < AD) ? v[a] * inv : 0.f;
        bmf[(size_t)(mt * 64 + (a >> 3) * 16 + col) * 8 + (a & 7)] = f2bf(val);
    }
}

__global__ void softmax_pi(const float* __restrict__ il, float* __restrict__ pi) {
    const int tid = threadIdx.x;   // 1024
    __shared__ float red[1024];
    const float v = il[tid];
    red[tid] = v; __syncthreads();
    for (int s = 512; s > 0; s >>= 1) { if (tid < s) red[tid] = fmaxf(red[tid], red[tid + s]); __syncthreads(); }
    const float m = red[0]; __syncthreads();
    const float e = expf(v - m);
    red[tid] = e; __syncthreads();
    for (int s = 512; s > 0; s >>= 1) { if (tid < s) red[tid] += red[tid + s]; __syncthreads(); }
    pi[tid] = e / red[0];
}

// Cooperative scan: 128 WGs x 256 threads = 32 q-slices x 4 INDEPENDENT batch domains
// (32 batches each). Domains never synchronize with each other (disjoint alpha rows,
// slots, outputs) -- jitter does not accumulate grid-wide.
// Sync within a domain: slot barrier with NO atomics. Producer: plain agent store
// slots[bg][qs] = t+1 (after vmcnt drain of alpha stores + syncthreads). Consumer:
// one coalesced wave-wide load of all 32 slots + __ballot, s_sleep backoff.
// Consumer-side normalization: c_t[b] = sum_q alpha_hat via ones-A MFMA chains.
__launch_bounds__(256)
__global__ void hmm_scan(const float* __restrict__ inputs,
                         const unsigned short* __restrict__ tf,
                         const unsigned short* __restrict__ bmf,
                         const float* __restrict__ pi,
                         unsigned short* __restrict__ abuf,   // 2 x [BD][QD] bf16
                         unsigned int* __restrict__ slots,    // [4][64] uint, zeroed
                         float* __restrict__ out) {
    __shared__ unsigned short ts[2 * 32 * 64 * 8];   // 64 KB T^T A-frags
    __shared__ unsigned short int_t[32 * 32];        // inputs[32 b][a] bf16, pad 32
    __shared__ float cbuf[32];

    const int tid   = threadIdx.x;
    const int wave  = tid >> 6;
    const int lane  = tid & 63;
    const int quad  = lane >> 4;
    const int col   = lane & 15;
    const int mtl   = wave & 1;        // m-tile within the 32 q_out
    const int bhalf = wave >> 1;       // which 16 of the 32 batches
    const int qs    = (int)blockIdx.x >> 2;  // 0..31
    const int bg    = (int)blockIdx.x & 3;   // domain 0..3
    const int bdom  = bg * 32;               // domain batch base
    const int bbase = bdom + bhalf * 16;     // wave batch base
    const int qrow  = qs * 32 + mtl * 16 + quad * 4;
    unsigned int* myslots = slots + bg * 64;

    // T^T slice into LDS (contiguous 64 KB).
    {
        const float4* src = (const float4*)(tf + (size_t)(qs * 2) * 32 * 64 * 8);
        float4* dst = (float4*)ts;
        for (int i = tid; i < 4096; i += 256) dst[i] = src[i];
    }
    const bf16x8 bmA = *(const bf16x8*)&bmf[(size_t)((qs * 2 + mtl) * 64 + lane) * 8];
    float pr[4];
    #pragma unroll
    for (int r = 0; r < 4; ++r) pr[r] = pi[qrow + r];

    bf16x8 ones;
    #pragma unroll
    for (int i = 0; i < 8; ++i) ones[i] = (short)0x3F80;

    const f32x4 fz = {0.f, 0.f, 0.f, 0.f};
    float ll = 0.f;

    // Prologue: stage inputs(0), emissions(0).
    for (int idx = tid; idx < 32 * 32; idx += 256) {
        const int row = idx >> 5, a = idx & 31;
        const float v = (a < AD) ? inputs[((size_t)(bdom + row) * LD) * AD + a] : 0.f;
        int_t[idx] = f2bf(v);
    }
    __syncthreads();
    f32x4 e, acc = fz, on = fz;
    {
        bf16x8 x = *(const bf16x8*)&int_t[(bhalf * 16 + col) * 32 + quad * 8];
        e = __builtin_amdgcn_mfma_f32_16x16x32_bf16(bmA, x, fz, 0, 0, 0);
    }

    for (int t = 0; t < LD; ++t) {
        // alpha_t tile from acc/on (computed from alpha(t-1) last iteration).
        float v0[4];
        if (t == 0) {
            #pragma unroll
            for (int r = 0; r < 4; ++r) v0[r] = pr[r] * e[r];
        } else {
            const float i0 = 1.f / on[0];
            #pragma unroll
            for (int r = 0; r < 4; ++r) v0[r] = acc[r] * e[r] * i0;
        }
        unsigned short* aw = abuf + (size_t)(t & 1) * BD * QD;
        ushort4 s0;
        s0.x = f2bf(v0[0]); s0.y = f2bf(v0[1]); s0.z = f2bf(v0[2]); s0.w = f2bf(v0[3]);
        store_a8(&aw[(size_t)(bbase + col) * QD + qrow], s0);

        if (t > 0 && mtl == 0 && quad == 0) cbuf[bhalf * 16 + col] = on[0];
        asm volatile("s_waitcnt vmcnt(0)" ::: "memory");  // drain this wave's alpha store
        __syncthreads();                                  // all waves drained; cbuf ready
        if (tid == 0)   // publish arrival: plain scoped store, no RMW
            __hip_atomic_store(&myslots[qs], (unsigned)(t + 1),
                               __ATOMIC_RELAXED, __HIP_MEMORY_SCOPE_AGENT);
        if (t > 0 && tid < 32) ll += logf(cbuf[tid]);

        if (t + 1 < LD) {
            // Hidden behind peers' arrival: stage inputs(t+1) + emissions(t+1).
            for (int idx = tid; idx < 32 * 32; idx += 256) {
                const int row = idx >> 5, a = idx & 31;
                const float v = (a < AD)
                    ? inputs[((size_t)(bdom + row) * LD + (t + 1)) * AD + a] : 0.f;
                int_t[idx] = f2bf(v);
            }
            __syncthreads();
            bf16x8 x = *(const bf16x8*)&int_t[(bhalf * 16 + col) * 32 + quad * 8];
            e = __builtin_amdgcn_mfma_f32_16x16x32_bf16(bmA, x, fz, 0, 0, 0);

            // Slot barrier: wave 0 polls all 32 domain slots with one coalesced load.
            if (wave == 0) {
                const unsigned target = (unsigned)(t + 1);
                for (;;) {
                    unsigned v = __hip_atomic_load(&myslots[lane & 31],
                                                   __ATOMIC_RELAXED, __HIP_MEMORY_SCOPE_AGENT);
                    if (__ballot(v >= target) == ~0ULL) break;
                    __builtin_amdgcn_s_sleep(1);
                }
            }
            __syncthreads();

            // Consume alpha(t): LLC loads + MFMA chains -> acc/on for step t+1.
            acc = fz; on = fz;
            const unsigned short* ab = abuf + (size_t)(t & 1) * BD * QD;
            const unsigned short* arow = ab + (size_t)(bbase + col) * QD + quad * 8;
            #pragma unroll 8
            for (int kt = 0; kt < 32; ++kt) {
                bf16x8 af = *(const bf16x8*)&ts[(size_t)((mtl * 32 + kt) * 64 + lane) * 8];
                bf16x8 b  = load_a16(&arow[(size_t)kt * 32]);
                acc = __builtin_amdgcn_mfma_f32_16x16x32_bf16(af, b, acc, 0, 0, 0);
                on  = __builtin_amdgcn_mfma_f32_16x16x32_bf16(ones, b, on, 0, 0, 0);
            }
        }
    }

    // Final normalizer c_{L-1}: only qs==0 WG of each domain.
    if (qs == 0) {
        if (wave == 0) {
            for (;;) {
                unsigned v = __hip_atomic_load(&myslots[lane & 31],
                                               __ATOMIC_RELAXED, __HIP_MEMORY_SCOPE_AGENT);
                if (__ballot(v >= (unsigned)LD) == ~0ULL) break;
                __builtin_amdgcn_s_sleep(1);
            }
        }
        __syncthreads();
        const unsigned short* ab = abuf + (size_t)((LD - 1) & 1) * BD * QD;
        const unsigned short* arow = ab + (size_t)(bbase + col) * QD + quad * 8;
        f32x4 f0 = fz;
        #pragma unroll 8
        for (int kt = 0; kt < 32; ++kt) {
            bf16x8 b = load_a16(&arow[(size_t)kt * 32]);
            f0 = __builtin_amdgcn_mfma_f32_16x16x32_bf16(ones, b, f0, 0, 0, 0);
        }
        if (mtl == 0 && quad == 0) cbuf[bhalf * 16 + col] = f0[0];
        __syncthreads();
        if (tid < 32) out[bdom + tid] = ll + logf(cbuf[tid]);
    }
}

extern "C" void kernel_launch(void* const* d_in, const int* in_sizes, int n_in,
                              void* d_out, int out_size, void* d_ws, size_t ws_size,
                              hipStream_t stream) {
    const float* inputs       = (const float*)d_in[0];
    const float* init_logits  = (const float*)d_in[1];
    const float* trans_logits = (const float*)d_in[2];
    const float* emis_logits  = (const float*)d_in[3];
    float* out = (float*)d_out;

    unsigned short* tf  = (unsigned short*)d_ws;                 // 2 MB
    unsigned short* bmf = tf + (size_t)QD * QD;                  // 64 KB
    float* pi           = (float*)(bmf + (size_t)QD * 32);       // 4 KB
    unsigned short* ab  = (unsigned short*)(pi + QD);            // 512 KB
    unsigned int* slots = (unsigned int*)(ab + (size_t)2 * BD * QD);  // 4x64 uint

    hipMemsetAsync(slots, 0, 4 * 64 * sizeof(unsigned int), stream);

    softmax_pack_T<<<1024, 256, 0, stream>>>(trans_logits, tf);
    softmax_pack_B<<<4, 256, 0, stream>>>(emis_logits, bmf);
    softmax_pi<<<1, 1024, 0, stream>>>(init_logits, pi);

    void* args[] = {(void*)&inputs, (void*)&tf, (void*)&bmf, (void*)&pi,
                    (void*)&ab, (void*)&slots, (void*)&out};
    hipLaunchCooperativeKernel((const void*)hmm_scan, dim3(NWG), dim3(256),
                               args, 0, stream);
}

// Round 6
// 11003.290 us; speedup vs baseline: 1.6331x; 1.0542x over previous
//
#include <hip/hip_runtime.h>
#include <hip/hip_bf16.h>

#define QD 1024
#define AD 26
#define BD 128
#define LD 1024
#define NWG 128          // 32 q-slices x 4 batch-domains
#define SLOT_STRIDE 32   // uints per slot = 128 B, one LLC line each
#define DOM_SLOTS 128    // (qs:32) x (mtl:2) x (bhalf:2)

typedef short bf16x8 __attribute__((ext_vector_type(8)));
typedef float f32x4 __attribute__((ext_vector_type(4)));

static __device__ __forceinline__ unsigned short f2bf(float f) {
    __hip_bfloat16 h = __float2bfloat16(f);
    return *reinterpret_cast<unsigned short*>(&h);
}

// Agent-scope relaxed 16B load as two 8B atomic loads (bypass stale L1/L2; LLC-served).
static __device__ __forceinline__ bf16x8 load_a16(const unsigned short* p) {
    unsigned long long lo = __hip_atomic_load((const unsigned long long*)p,
                                              __ATOMIC_RELAXED, __HIP_MEMORY_SCOPE_AGENT);
    unsigned long long hi = __hip_atomic_load((const unsigned long long*)(p + 4),
                                              __ATOMIC_RELAXED, __HIP_MEMORY_SCOPE_AGENT);
    union { unsigned long long q[2]; bf16x8 v; } u;
    u.q[0] = lo; u.q[1] = hi;
    return u.v;
}

// Agent-scope relaxed 8B store (write-through past per-XCD L2; visible once vmcnt retires).
static __device__ __forceinline__ void store_a8(unsigned short* p, ushort4 v) {
    union { ushort4 s; unsigned long long q; } u; u.s = v;
    __hip_atomic_store((unsigned long long*)p, u.q,
                       __ATOMIC_RELAXED, __HIP_MEMORY_SCOPE_AGENT);
}

// Row-softmax of trans_logits [1024,1024] -> bf16 packed as A-fragments of T^T.
// A-frag layout (16x16x32): A[m = lane&15][k = quad*8 + j].
__global__ void softmax_pack_T(const float* __restrict__ tl, unsigned short* __restrict__ tf) {
    const int i = blockIdx.x;      // q_in
    const int tid = threadIdx.x;   // 256
    __shared__ float red[256];
    float v[4];
    float m = -1e30f;
    for (int c = 0; c < 4; ++c) { v[c] = tl[i * QD + tid + 256 * c]; m = fmaxf(m, v[c]); }
    red[tid] = m; __syncthreads();
    for (int s = 128; s > 0; s >>= 1) { if (tid < s) red[tid] = fmaxf(red[tid], red[tid + s]); __syncthreads(); }
    m = red[0]; __syncthreads();
    float sum = 0.f;
    for (int c = 0; c < 4; ++c) { v[c] = expf(v[c] - m); sum += v[c]; }
    red[tid] = sum; __syncthreads();
    for (int s = 128; s > 0; s >>= 1) { if (tid < s) red[tid] += red[tid + s]; __syncthreads(); }
    const float inv = 1.0f / red[0];
    const int kt = i >> 5, quad = (i >> 3) & 3, j = i & 7;
    for (int c = 0; c < 4; ++c) {
        const int q = tid + 256 * c;
        const int mt = q >> 4, col = q & 15;
        tf[(size_t)((mt * 32 + kt) * 64 + quad * 16 + col) * 8 + j] = f2bf(v[c] * inv);
    }
}

// Row-softmax of emis_logits [1024,26] -> bf16 A-fragments (M=q, K=a padded to 32).
__global__ void softmax_pack_B(const float* __restrict__ el, unsigned short* __restrict__ bmf) {
    const int q = blockIdx.x * blockDim.x + threadIdx.x;
    if (q >= QD) return;
    float v[AD];
    float m = -1e30f;
    for (int a = 0; a < AD; ++a) { v[a] = el[q * AD + a]; m = fmaxf(m, v[a]); }
    float sum = 0.f;
    for (int a = 0; a < AD; ++a) { v[a] = expf(v[a] - m); sum += v[a]; }
    const float inv = 1.0f / sum;
    const int mt = q >> 4, col = q & 15;
    for (int a = 0; a < 32; ++a) {
        const float val = (a < AD) ? v[a] * inv : 0.f;
        bmf[(size_t)(mt * 64 + (a >> 3) * 16 + col) * 8 + (a & 7)] = f2bf(val);
    }
}

__global__ void softmax_pi(const float* __restrict__ il, float* __restrict__ pi) {
    const int tid = threadIdx.x;   // 1024
    __shared__ float red[1024];
    const float v = il[tid];
    red[tid] = v; __syncthreads();
    for (int s = 512; s > 0; s >>= 1) { if (tid < s) red[tid] = fmaxf(red[tid], red[tid + s]); __syncthreads(); }
    const float m = red[0]; __syncthreads();
    const float e = expf(v - m);
    red[tid] = e; __syncthreads();
    for (int s = 512; s > 0; s >>= 1) { if (tid < s) red[tid] += red[tid + s]; __syncthreads(); }
    pi[tid] = e / red[0];
}

// Cooperative scan: 128 WGs x 256 threads = 32 q-slices x 4 independent batch domains.
// ZERO intra-WG synchronization in the steady-state loop: each of the 512 waves is an
// independent agent. Wave (qs, mtl, bhalf, bg) owns tile q=[qs*32+mtl*16,+16) x
// b=[bg*32+bhalf*16,+16). Per step: compute tile -> 8B scoped store -> wave-local
// vmcnt drain -> publish own slot (one 128-B line per producer wave) -> emission for
// t+1 via direct register loads -> 64-lane coalesced ballot poll of the 64 relevant
// producer slots -> consume alpha(t) with 32 fixed-order kt MFMA pairs.
// Consumer-side normalization: on[0] = colsum = c_t[own batch] (identical in all
// lanes of a column, bit-exact across WGs due to fixed consume order).
__launch_bounds__(256)
__global__ void hmm_scan(const float* __restrict__ inputs,
                         const unsigned short* __restrict__ tf,
                         const unsigned short* __restrict__ bmf,
                         const float* __restrict__ pi,
                         unsigned short* __restrict__ abuf,   // 2 x [BD][QD] bf16
                         unsigned int* __restrict__ slots,    // [4][128][32] uint, zeroed
                         float* __restrict__ out) {
    __shared__ unsigned short ts[2 * 32 * 64 * 8];   // 64 KB T^T A-frags for this q-slice

    const int tid   = threadIdx.x;
    const int wave  = tid >> 6;
    const int lane  = tid & 63;
    const int quad  = lane >> 4;
    const int col   = lane & 15;
    const int mtl   = wave & 1;              // m-tile within 32 q_out
    const int bhalf = wave >> 1;             // which 16 of the 32 domain batches
    const int qs    = (int)blockIdx.x >> 2;  // 0..31
    const int bg    = (int)blockIdx.x & 3;   // domain
    const int bdom  = bg * 32;
    const int bbase = bdom + bhalf * 16;
    const int b     = bbase + col;           // this lane's batch
    const int qrow  = qs * 32 + mtl * 16 + quad * 4;

    unsigned int* dom = slots + (size_t)bg * DOM_SLOTS * SLOT_STRIDE;
    unsigned int* myslot = dom + (size_t)(((qs * 2 + mtl) * 2) + bhalf) * SLOT_STRIDE;
    // Poll set: lane L -> producer (qs=L>>1, mtl=L&1) with our bhalf.
    const unsigned int* pollp = dom + (size_t)(lane * 2 + bhalf) * SLOT_STRIDE;

    // T^T slice into LDS (contiguous 64 KB), once.
    {
        const float4* src = (const float4*)(tf + (size_t)(qs * 2) * 32 * 64 * 8);
        float4* dst = (float4*)ts;
        for (int i = tid; i < 4096; i += 256) dst[i] = src[i];
    }
    const bf16x8 bmA = *(const bf16x8*)&bmf[(size_t)((qs * 2 + mtl) * 64 + lane) * 8];
    float pr[4];
    #pragma unroll
    for (int r = 0; r < 4; ++r) pr[r] = pi[qrow + r];

    bf16x8 ones;
    #pragma unroll
    for (int i = 0; i < 8; ++i) ones[i] = (short)0x3F80;

    const f32x4 fz = {0.f, 0.f, 0.f, 0.f};
    float ll = 0.f;
    __syncthreads();   // ts ready (only barrier outside the loop epilogue)

    // Emission(0) directly into registers: lane needs inputs[b][0][quad*8+j].
    f32x4 e;
    {
        bf16x8 xb;
        #pragma unroll
        for (int j = 0; j < 8; ++j) {
            const int a = quad * 8 + j;
            const float v = (a < AD) ? inputs[(size_t)b * LD * AD + a] : 0.f;
            xb[j] = (short)f2bf(v);
        }
        e = __builtin_amdgcn_mfma_f32_16x16x32_bf16(bmA, xb, fz, 0, 0, 0);
    }

    f32x4 acc = fz, on = fz;

    for (int t = 0; t < LD; ++t) {
        float v0[4];
        if (t == 0) {
            #pragma unroll
            for (int r = 0; r < 4; ++r) v0[r] = pr[r] * e[r];
        } else {
            const float i0 = 1.f / on[0];
            #pragma unroll
            for (int r = 0; r < 4; ++r) v0[r] = acc[r] * e[r] * i0;
        }
        unsigned short* aw = abuf + (size_t)(t & 1) * BD * QD;
        ushort4 s0;
        s0.x = f2bf(v0[0]); s0.y = f2bf(v0[1]); s0.z = f2bf(v0[2]); s0.w = f2bf(v0[3]);
        store_a8(&aw[(size_t)b * QD + qrow], s0);

        asm volatile("s_waitcnt vmcnt(0)" ::: "memory");   // wave-local store drain
        if (lane == 0)
            __hip_atomic_store(myslot, (unsigned)(t + 1),
                               __ATOMIC_RELAXED, __HIP_MEMORY_SCOPE_AGENT);
        if (t > 0) ll += logf(on[0]);   // on[0] == c_t-1[this lane's batch]

        if (t + 1 < LD) {
            // Emission(t+1): direct register loads (overlaps peers' publication).
            bf16x8 xb;
            #pragma unroll
            for (int j = 0; j < 8; ++j) {
                const int a = quad * 8 + j;
                const float v = (a < AD)
                    ? inputs[((size_t)b * LD + (t + 1)) * AD + a] : 0.f;
                xb[j] = (short)f2bf(v);
            }
            e = __builtin_amdgcn_mfma_f32_16x16x32_bf16(bmA, xb, fz, 0, 0, 0);

            // Wave-local slot barrier: one coalesced load of 64 producer slots.
            {
                const unsigned target = (unsigned)(t + 1);
                for (;;) {
                    unsigned v = __hip_atomic_load(pollp, __ATOMIC_RELAXED,
                                                   __HIP_MEMORY_SCOPE_AGENT);
                    if (__ballot(v >= target) == ~0ULL) break;
                    __builtin_amdgcn_s_sleep(1);
                }
            }

            // Consume alpha(t): fixed order kt=0..31 (bit-exact across WGs).
            acc = fz; on = fz;
            const unsigned short* arow =
                abuf + (size_t)(t & 1) * BD * QD + (size_t)b * QD + quad * 8;
            #pragma unroll 8
            for (int kt = 0; kt < 32; ++kt) {
                bf16x8 af = *(const bf16x8*)&ts[(size_t)((mtl * 32 + kt) * 64 + lane) * 8];
                bf16x8 bfr = load_a16(&arow[(size_t)kt * 32]);
                acc = __builtin_amdgcn_mfma_f32_16x16x32_bf16(af, bfr, acc, 0, 0, 0);
                on  = __builtin_amdgcn_mfma_f32_16x16x32_bf16(ones, bfr, on, 0, 0, 0);
            }
        }
    }

    // Final normalizer c_{L-1}; only qs==0 WGs produce output.
    if (qs == 0) {
        for (;;) {
            unsigned v = __hip_atomic_load(pollp, __ATOMIC_RELAXED,
                                           __HIP_MEMORY_SCOPE_AGENT);
            if (__ballot(v >= (unsigned)LD) == ~0ULL) break;
            __builtin_amdgcn_s_sleep(1);
        }
        const unsigned short* arow =
            abuf + (size_t)((LD - 1) & 1) * BD * QD + (size_t)b * QD + quad * 8;
        f32x4 f0 = fz;
        #pragma unroll 8
        for (int kt = 0; kt < 32; ++kt) {
            bf16x8 bfr = load_a16(&arow[(size_t)kt * 32]);
            f0 = __builtin_amdgcn_mfma_f32_16x16x32_bf16(ones, bfr, f0, 0, 0, 0);
        }
        if (mtl == 0 && quad == 0) out[b] = ll + logf(f0[0]);
    }
}

extern "C" void kernel_launch(void* const* d_in, const int* in_sizes, int n_in,
                              void* d_out, int out_size, void* d_ws, size_t ws_size,
                              hipStream_t stream) {
    const float* inputs       = (const float*)d_in[0];
    const float* init_logits  = (const float*)d_in[1];
    const float* trans_logits = (const float*)d_in[2];
    const float* emis_logits  = (const float*)d_in[3];
    float* out = (float*)d_out;

    unsigned short* tf  = (unsigned short*)d_ws;                 // 2 MB
    unsigned short* bmf = tf + (size_t)QD * QD;                  // 64 KB
    float* pi           = (float*)(bmf + (size_t)QD * 32);       // 4 KB
    unsigned short* ab  = (unsigned short*)(pi + QD);            // 512 KB
    unsigned int* slots = (unsigned int*)(ab + (size_t)2 * BD * QD);  // 64 KB

    hipMemsetAsync(slots, 0, (size_t)4 * DOM_SLOTS * SLOT_STRIDE * sizeof(unsigned int),
                   stream);

    softmax_pack_T<<<1024, 256, 0, stream>>>(trans_logits, tf);
    softmax_pack_B<<<4, 256, 0, stream>>>(emis_logits, bmf);
    softmax_pi<<<1, 1024, 0, stream>>>(init_logits, pi);

    void* args[] = {(void*)&inputs, (void*)&tf, (void*)&bmf, (void*)&pi,
                    (void*)&ab, (void*)&slots, (void*)&out};
    hipLaunchCooperativeKernel((const void*)hmm_scan, dim3(NWG), dim3(256),
                               args, 0, stream);
}

// Round 7
// 8690.334 us; speedup vs baseline: 2.0677x; 1.2662x over previous
//
#include <hip/hip_runtime.h>
#include <hip/hip_bf16.h>

#define QD 1024
#define AD 26
#define BD 128
#define LD 1024
#define NWG 128          // 32 q-slices x 4 batch-domains
#define SLOT_STRIDE 32   // uints per slot = 128 B line each
#define DOM_SLOTS 128
#define PSTR (8 * 32 * 64 * 8)   // ushorts per parity of packed alpha (256 KB)

typedef short bf16x8 __attribute__((ext_vector_type(8)));
typedef float f32x4 __attribute__((ext_vector_type(4)));

static __device__ __forceinline__ unsigned short f2bf(float f) {
    __hip_bfloat16 h = __float2bfloat16(f);
    return *reinterpret_cast<unsigned short*>(&h);
}

// Agent-scope relaxed 16B load (two 8B scoped loads; plain loads w/ sc bits -> coalesce).
static __device__ __forceinline__ bf16x8 load_a16(const unsigned short* p) {
    unsigned long long lo = __hip_atomic_load((const unsigned long long*)p,
                                              __ATOMIC_RELAXED, __HIP_MEMORY_SCOPE_AGENT);
    unsigned long long hi = __hip_atomic_load((const unsigned long long*)(p + 4),
                                              __ATOMIC_RELAXED, __HIP_MEMORY_SCOPE_AGENT);
    union { unsigned long long q[2]; bf16x8 v; } u;
    u.q[0] = lo; u.q[1] = hi;
    return u.v;
}

// Agent-scope relaxed 8B store (write-through; visible once vmcnt retires).
static __device__ __forceinline__ void store_a8(unsigned short* p, ushort4 v) {
    union { ushort4 s; unsigned long long q; } u; u.s = v;
    __hip_atomic_store((unsigned long long*)p, u.q,
                       __ATOMIC_RELAXED, __HIP_MEMORY_SCOPE_AGENT);
}

// Row-softmax of trans_logits [1024,1024] -> bf16 packed as A-fragments of T^T.
// A-frag layout (16x16x32): A[m = lane&15][k = quad*8 + j].
__global__ void softmax_pack_T(const float* __restrict__ tl, unsigned short* __restrict__ tf) {
    const int i = blockIdx.x;      // q_in
    const int tid = threadIdx.x;   // 256
    __shared__ float red[256];
    float v[4];
    float m = -1e30f;
    for (int c = 0; c < 4; ++c) { v[c] = tl[i * QD + tid + 256 * c]; m = fmaxf(m, v[c]); }
    red[tid] = m; __syncthreads();
    for (int s = 128; s > 0; s >>= 1) { if (tid < s) red[tid] = fmaxf(red[tid], red[tid + s]); __syncthreads(); }
    m = red[0]; __syncthreads();
    float sum = 0.f;
    for (int c = 0; c < 4; ++c) { v[c] = expf(v[c] - m); sum += v[c]; }
    red[tid] = sum; __syncthreads();
    for (int s = 128; s > 0; s >>= 1) { if (tid < s) red[tid] += red[tid + s]; __syncthreads(); }
    const float inv = 1.0f / red[0];
    const int kt = i >> 5, quad = (i >> 3) & 3, j = i & 7;
    for (int c = 0; c < 4; ++c) {
        const int q = tid + 256 * c;
        const int mt = q >> 4, col = q & 15;
        tf[(size_t)((mt * 32 + kt) * 64 + quad * 16 + col) * 8 + j] = f2bf(v[c] * inv);
    }
}

// Row-softmax of emis_logits [1024,26] -> bf16 A-fragments (M=q, K=a padded to 32).
__global__ void softmax_pack_B(const float* __restrict__ el, unsigned short* __restrict__ bmf) {
    const int q = blockIdx.x * blockDim.x + threadIdx.x;
    if (q >= QD) return;
    float v[AD];
    float m = -1e30f;
    for (int a = 0; a < AD; ++a) { v[a] = el[q * AD + a]; m = fmaxf(m, v[a]); }
    float sum = 0.f;
    for (int a = 0; a < AD; ++a) { v[a] = expf(v[a] - m); sum += v[a]; }
    const float inv = 1.0f / sum;
    const int mt = q >> 4, col = q & 15;
    for (int a = 0; a < 32; ++a) {
        const float val = (a < AD) ? v[a] * inv : 0.f;
        bmf[(size_t)(mt * 64 + (a >> 3) * 16 + col) * 8 + (a & 7)] = f2bf(val);
    }
}

__global__ void softmax_pi(const float* __restrict__ il, float* __restrict__ pi) {
    const int tid = threadIdx.x;   // 1024
    __shared__ float red[1024];
    const float v = il[tid];
    red[tid] = v; __syncthreads();
    for (int s = 512; s > 0; s >>= 1) { if (tid < s) red[tid] = fmaxf(red[tid], red[tid + s]); __syncthreads(); }
    const float m = red[0]; __syncthreads();
    const float e = expf(v - m);
    red[tid] = e; __syncthreads();
    for (int s = 512; s > 0; s >>= 1) { if (tid < s) red[tid] += red[tid + s]; __syncthreads(); }
    pi[tid] = e / red[0];
}

// Cooperative scan, 128 WGs x 256 threads = 32 q-slices x 4 independent batch domains.
// 512 independent waves; zero LDS; zero intra-WG sync in the loop.
// Alpha exchange is FRAGMENT-PACKED: producer wave (qs,mtl,bhalf,bg) stores its
// ushort4 C-tile values directly into the consumer's B-fragment slot:
//   quad_c = mtl*2 + (quad>>1), j0 = (quad&1)*4, lane_c = quad_c*16+col
//   apack[parity][bg*2+bhalf][kt=qs][lane_c][j0..j0+3]
// Consumer reads chunk kt as ONE 16-B/lane coalesced load (1 KB contiguous per wave).
// T A-frags live in registers (32 frags = 128 VGPR; 1 wave/SIMD so no occupancy cost).
// Consumer-side normalization via ones-A MFMA (on[0] = c_t[lane's batch]).
__launch_bounds__(256)
__global__ void hmm_scan(const float* __restrict__ inputs,
                         const unsigned short* __restrict__ tf,
                         const unsigned short* __restrict__ bmf,
                         const float* __restrict__ pi,
                         unsigned short* __restrict__ apack,  // 2 x PSTR ushorts
                         unsigned int* __restrict__ slots,    // [4][128][32] uint, zeroed
                         float* __restrict__ out) {
    const int tid   = threadIdx.x;
    const int wave  = tid >> 6;
    const int lane  = tid & 63;
    const int quad  = lane >> 4;
    const int col   = lane & 15;
    const int mtl   = wave & 1;
    const int bhalf = wave >> 1;
    const int qs    = (int)blockIdx.x >> 2;
    const int bg    = (int)blockIdx.x & 3;
    const int b     = bg * 32 + bhalf * 16 + col;   // this lane's batch
    const int qrow  = qs * 32 + mtl * 16 + quad * 4;
    const int grp   = bg * 2 + bhalf;               // packed group

    unsigned int* dom = slots + (size_t)bg * DOM_SLOTS * SLOT_STRIDE;
    unsigned int* myslot = dom + (size_t)((qs * 2 + mtl) * 2 + bhalf) * SLOT_STRIDE;
    const unsigned int* pollp = dom + (size_t)(lane * 2 + bhalf) * SLOT_STRIDE;

    // Producer store target (ushort offset within a parity).
    const int lane_c = (mtl * 2 + (quad >> 1)) * 16 + col;
    const size_t poff = (size_t)((grp * 32 + qs) * 64 + lane_c) * 8 + (quad & 1) * 4;
    // Consumer chunk base (ushort offset within a parity); chunk kt at +kt*512.
    const size_t coff = (size_t)(grp * 32) * 512 + (size_t)lane * 8;

    // All 32 T^T A-frags into registers (AGPR/VGPR unified file; 1 wave/SIMD).
    bf16x8 tfr[32];
    {
        const bf16x8* tsrc = (const bf16x8*)tf + (size_t)(qs * 2 + mtl) * 32 * 64 + lane;
        #pragma unroll
        for (int kt = 0; kt < 32; ++kt) tfr[kt] = tsrc[(size_t)kt * 64];
    }
    const bf16x8 bmA = *(const bf16x8*)&bmf[(size_t)((qs * 2 + mtl) * 64 + lane) * 8];
    float pr[4];
    #pragma unroll
    for (int r = 0; r < 4; ++r) pr[r] = pi[qrow + r];

    bf16x8 ones;
    #pragma unroll
    for (int i = 0; i < 8; ++i) ones[i] = (short)0x3F80;

    const f32x4 fz = {0.f, 0.f, 0.f, 0.f};
    float ll = 0.f;

    // Emission(0): direct register loads.
    f32x4 e;
    {
        bf16x8 xb;
        #pragma unroll
        for (int j = 0; j < 8; ++j) {
            const int a = quad * 8 + j;
            const float v = (a < AD) ? inputs[(size_t)b * LD * AD + a] : 0.f;
            xb[j] = (short)f2bf(v);
        }
        e = __builtin_amdgcn_mfma_f32_16x16x32_bf16(bmA, xb, fz, 0, 0, 0);
    }

    f32x4 acc = fz, on = fz;

    for (int t = 0; t < LD; ++t) {
        float v0[4];
        if (t == 0) {
            #pragma unroll
            for (int r = 0; r < 4; ++r) v0[r] = pr[r] * e[r];
        } else {
            const float i0 = 1.f / on[0];
            #pragma unroll
            for (int r = 0; r < 4; ++r) v0[r] = acc[r] * e[r] * i0;
        }
        ushort4 s0;
        s0.x = f2bf(v0[0]); s0.y = f2bf(v0[1]); s0.z = f2bf(v0[2]); s0.w = f2bf(v0[3]);
        store_a8(apack + (size_t)(t & 1) * PSTR + poff, s0);

        asm volatile("s_waitcnt vmcnt(0)" ::: "memory");   // wave-local store drain
        if (lane == 0)
            __hip_atomic_store(myslot, (unsigned)(t + 1),
                               __ATOMIC_RELAXED, __HIP_MEMORY_SCOPE_AGENT);
        if (qs == 0 && t > 0) ll += logf(on[0]);   // on[0] == c_{t-1}[lane's batch]

        if (t + 1 < LD) {
            // Emission(t+1) while peers publish.
            bf16x8 xb;
            #pragma unroll
            for (int j = 0; j < 8; ++j) {
                const int a = quad * 8 + j;
                const float v = (a < AD)
                    ? inputs[((size_t)b * LD + (t + 1)) * AD + a] : 0.f;
                xb[j] = (short)f2bf(v);
            }
            e = __builtin_amdgcn_mfma_f32_16x16x32_bf16(bmA, xb, fz, 0, 0, 0);

            // Wave-local slot barrier: one coalesced load of the 64 producer slots.
            {
                const unsigned target = (unsigned)(t + 1);
                for (;;) {
                    unsigned v = __hip_atomic_load(pollp, __ATOMIC_RELAXED,
                                                   __HIP_MEMORY_SCOPE_AGENT);
                    if (__ballot(v >= target) == ~0ULL) break;
                    __builtin_amdgcn_s_sleep(2);
                }
            }

            // Consume alpha(t): 32 coalesced B-frag loads + 64 MFMA, pipelined.
            acc = fz; on = fz;
            const unsigned short* cp = apack + (size_t)(t & 1) * PSTR + coff;
            #pragma unroll 4
            for (int kt = 0; kt < 32; ++kt) {
                bf16x8 bfr = load_a16(cp + (size_t)kt * 512);
                acc = __builtin_amdgcn_mfma_f32_16x16x32_bf16(tfr[kt], bfr, acc, 0, 0, 0);
                on  = __builtin_amdgcn_mfma_f32_16x16x32_bf16(ones, bfr, on, 0, 0, 0);
            }
        }
    }

    // Final normalizer c_{L-1}; only qs==0 waves produce output.
    if (qs == 0) {
        for (;;) {
            unsigned v = __hip_atomic_load(pollp, __ATOMIC_RELAXED,
                                           __HIP_MEMORY_SCOPE_AGENT);
            if (__ballot(v >= (unsigned)LD) == ~0ULL) break;
            __builtin_amdgcn_s_sleep(2);
        }
        const unsigned short* cp = apack + (size_t)((LD - 1) & 1) * PSTR + coff;
        f32x4 f0 = fz;
        #pragma unroll 4
        for (int kt = 0; kt < 32; ++kt) {
            bf16x8 bfr = load_a16(cp + (size_t)kt * 512);
            f0 = __builtin_amdgcn_mfma_f32_16x16x32_bf16(ones, bfr, f0, 0, 0, 0);
        }
        if (mtl == 0 && quad == 0) out[b] = ll + logf(f0[0]);
    }
}

extern "C" void kernel_launch(void* const* d_in, const int* in_sizes, int n_in,
                              void* d_out, int out_size, void* d_ws, size_t ws_size,
                              hipStream_t stream) {
    const float* inputs       = (const float*)d_in[0];
    const float* init_logits  = (const float*)d_in[1];
    const float* trans_logits = (const float*)d_in[2];
    const float* emis_logits  = (const float*)d_in[3];
    float* out = (float*)d_out;

    unsigned short* tf    = (unsigned short*)d_ws;                 // 2 MB
    unsigned short* bmf   = tf + (size_t)QD * QD;                  // 64 KB
    float* pi             = (float*)(bmf + (size_t)QD * 32);       // 4 KB
    unsigned short* apack = (unsigned short*)(pi + QD);            // 512 KB
    unsigned int* slots   = (unsigned int*)(apack + (size_t)2 * PSTR);  // 64 KB

    hipMemsetAsync(slots, 0, (size_t)4 * DOM_SLOTS * SLOT_STRIDE * sizeof(unsigned int),
                   stream);

    softmax_pack_T<<<1024, 256, 0, stream>>>(trans_logits, tf);
    softmax_pack_B<<<4, 256, 0, stream>>>(emis_logits, bmf);
    softmax_pi<<<1, 1024, 0, stream>>>(init_logits, pi);

    void* args[] = {(void*)&inputs, (void*)&tf, (void*)&bmf, (void*)&pi,
                    (void*)&apack, (void*)&slots, (void*)&out};
    hipLaunchCooperativeKernel((const void*)hmm_scan, dim3(NWG), dim3(256),
                               args, 0, stream);
}

// Round 8
// 5974.522 us; speedup vs baseline: 3.0076x; 1.4546x over previous
//
#include <hip/hip_runtime.h>
#include <hip/hip_bf16.h>

#define QD 1024
#define AD 26
#define BD 128
#define LD 1024
#define NWG 128          // 32 q-slices x 4 batch-domains
#define SLOT_STRIDE 32   // uints per slot = 128 B line each
#define DOM_SLOTS 128
#define PSTR (8 * 32 * 64 * 8)   // ushorts per parity of packed alpha (256 KB)

typedef short bf16x8 __attribute__((ext_vector_type(8)));
typedef float f32x4 __attribute__((ext_vector_type(4)));

static __device__ __forceinline__ unsigned short f2bf(float f) {
    __hip_bfloat16 h = __float2bfloat16(f);
    return *reinterpret_cast<unsigned short*>(&h);
}

// Agent-scope relaxed 16B load (two 8B scoped loads; sc0 sc1 -> bypass stale L1/L2).
static __device__ __forceinline__ bf16x8 load_a16(const unsigned short* p) {
    unsigned long long lo = __hip_atomic_load((const unsigned long long*)p,
                                              __ATOMIC_RELAXED, __HIP_MEMORY_SCOPE_AGENT);
    unsigned long long hi = __hip_atomic_load((const unsigned long long*)(p + 4),
                                              __ATOMIC_RELAXED, __HIP_MEMORY_SCOPE_AGENT);
    union { unsigned long long q[2]; bf16x8 v; } u;
    u.q[0] = lo; u.q[1] = hi;
    return u.v;
}

// Agent-scope relaxed 8B store (write-through; visible once vmcnt retires).
static __device__ __forceinline__ void store_a8(unsigned short* p, ushort4 v) {
    union { ushort4 s; unsigned long long q; } u; u.s = v;
    __hip_atomic_store((unsigned long long*)p, u.q,
                       __ATOMIC_RELAXED, __HIP_MEMORY_SCOPE_AGENT);
}

// Row-softmax of trans_logits [1024,1024] -> bf16 packed as A-fragments of T^T.
// A-frag layout (16x16x32): A[m = lane&15][k = quad*8 + j].
__global__ void softmax_pack_T(const float* __restrict__ tl, unsigned short* __restrict__ tf) {
    const int i = blockIdx.x;      // q_in
    const int tid = threadIdx.x;   // 256
    __shared__ float red[256];
    float v[4];
    float m = -1e30f;
    for (int c = 0; c < 4; ++c) { v[c] = tl[i * QD + tid + 256 * c]; m = fmaxf(m, v[c]); }
    red[tid] = m; __syncthreads();
    for (int s = 128; s > 0; s >>= 1) { if (tid < s) red[tid] = fmaxf(red[tid], red[tid + s]); __syncthreads(); }
    m = red[0]; __syncthreads();
    float sum = 0.f;
    for (int c = 0; c < 4; ++c) { v[c] = expf(v[c] - m); sum += v[c]; }
    red[tid] = sum; __syncthreads();
    for (int s = 128; s > 0; s >>= 1) { if (tid < s) red[tid] += red[tid + s]; __syncthreads(); }
    const float inv = 1.0f / red[0];
    const int kt = i >> 5, quad = (i >> 3) & 3, j = i & 7;
    for (int c = 0; c < 4; ++c) {
        const int q = tid + 256 * c;
        const int mt = q >> 4, col = q & 15;
        tf[(size_t)((mt * 32 + kt) * 64 + quad * 16 + col) * 8 + j] = f2bf(v[c] * inv);
    }
}

// Row-softmax of emis_logits [1024,26] -> bf16 A-fragments (M=q, K=a padded to 32).
__global__ void softmax_pack_B(const float* __restrict__ el, unsigned short* __restrict__ bmf) {
    const int q = blockIdx.x * blockDim.x + threadIdx.x;
    if (q >= QD) return;
    float v[AD];
    float m = -1e30f;
    for (int a = 0; a < AD; ++a) { v[a] = el[q * AD + a]; m = fmaxf(m, v[a]); }
    float sum = 0.f;
    for (int a = 0; a < AD; ++a) { v[a] = expf(v[a] - m); sum += v[a]; }
    const float inv = 1.0f / sum;
    const int mt = q >> 4, col = q & 15;
    for (int a = 0; a < 32; ++a) {
        const float val = (a < AD) ? v[a] * inv : 0.f;
        bmf[(size_t)(mt * 64 + (a >> 3) * 16 + col) * 8 + (a & 7)] = f2bf(val);
    }
}

__global__ void softmax_pi(const float* __restrict__ il, float* __restrict__ pi) {
    const int tid = threadIdx.x;   // 1024
    __shared__ float red[1024];
    const float v = il[tid];
    red[tid] = v; __syncthreads();
    for (int s = 512; s > 0; s >>= 1) { if (tid < s) red[tid] = fmaxf(red[tid], red[tid + s]); __syncthreads(); }
    const float m = red[0]; __syncthreads();
    const float e = expf(v - m);
    red[tid] = e; __syncthreads();
    for (int s = 512; s > 0; s >>= 1) { if (tid < s) red[tid] += red[tid + s]; __syncthreads(); }
    pi[tid] = e / red[0];
}

// Cooperative scan, 128 WGs x 256 threads = 32 q-slices x 4 independent batch domains.
// 512 independent waves; zero LDS; zero intra-WG sync in the loop.
// Alpha exchange is FRAGMENT-PACKED (producer stores its ushort4 C-values directly
// into the consumer's B-fragment slot; consumer reads each chunk as one 16-B/lane
// coalesced load). T A-frags live in AGPRs. Consume loop is SOFTWARE-PIPELINED:
// all 64 loads pre-issued into a 128-VGPR buffer array, then 64 MFMAs drain them
// with fine-grained vmcnt waits (~60 loads in flight vs ~4 before).
__launch_bounds__(256, 1)
__global__ void hmm_scan(const float* __restrict__ inputs,
                         const unsigned short* __restrict__ tf,
                         const unsigned short* __restrict__ bmf,
                         const float* __restrict__ pi,
                         unsigned short* __restrict__ apack,  // 2 x PSTR ushorts
                         unsigned int* __restrict__ slots,    // [4][128][32] uint, zeroed
                         float* __restrict__ out) {
    const int tid   = threadIdx.x;
    const int wave  = tid >> 6;
    const int lane  = tid & 63;
    const int quad  = lane >> 4;
    const int col   = lane & 15;
    const int mtl   = wave & 1;
    const int bhalf = wave >> 1;
    const int qs    = (int)blockIdx.x >> 2;
    const int bg    = (int)blockIdx.x & 3;
    const int b     = bg * 32 + bhalf * 16 + col;   // this lane's batch
    const int qrow  = qs * 32 + mtl * 16 + quad * 4;
    const int grp   = bg * 2 + bhalf;               // packed group

    unsigned int* dom = slots + (size_t)bg * DOM_SLOTS * SLOT_STRIDE;
    unsigned int* myslot = dom + (size_t)((qs * 2 + mtl) * 2 + bhalf) * SLOT_STRIDE;
    const unsigned int* pollp = dom + (size_t)(lane * 2 + bhalf) * SLOT_STRIDE;

    // Producer store target (ushort offset within a parity).
    const int lane_c = (mtl * 2 + (quad >> 1)) * 16 + col;
    const size_t poff = (size_t)((grp * 32 + qs) * 64 + lane_c) * 8 + (quad & 1) * 4;
    // Consumer chunk base (ushort offset within a parity); chunk kt at +kt*512.
    const size_t coff = (size_t)(grp * 32) * 512 + (size_t)lane * 8;

    // All 32 T^T A-frags into registers (AGPR side of the unified file).
    bf16x8 tfr[32];
    {
        const bf16x8* tsrc = (const bf16x8*)tf + (size_t)(qs * 2 + mtl) * 32 * 64 + lane;
        #pragma unroll
        for (int kt = 0; kt < 32; ++kt) tfr[kt] = tsrc[(size_t)kt * 64];
    }
    const bf16x8 bmA = *(const bf16x8*)&bmf[(size_t)((qs * 2 + mtl) * 64 + lane) * 8];
    float pr[4];
    #pragma unroll
    for (int r = 0; r < 4; ++r) pr[r] = pi[qrow + r];

    bf16x8 ones;
    #pragma unroll
    for (int i = 0; i < 8; ++i) ones[i] = (short)0x3F80;

    const f32x4 fz = {0.f, 0.f, 0.f, 0.f};
    float ll = 0.f;

    // Emission(0): direct register loads.
    f32x4 e;
    {
        bf16x8 xb;
        #pragma unroll
        for (int j = 0; j < 8; ++j) {
            const int a = quad * 8 + j;
            const float v = (a < AD) ? inputs[(size_t)b * LD * AD + a] : 0.f;
            xb[j] = (short)f2bf(v);
        }
        e = __builtin_amdgcn_mfma_f32_16x16x32_bf16(bmA, xb, fz, 0, 0, 0);
    }

    f32x4 acc = fz, on = fz;

    for (int t = 0; t < LD; ++t) {
        float v0[4];
        if (t == 0) {
            #pragma unroll
            for (int r = 0; r < 4; ++r) v0[r] = pr[r] * e[r];
        } else {
            const float i0 = 1.f / on[0];
            #pragma unroll
            for (int r = 0; r < 4; ++r) v0[r] = acc[r] * e[r] * i0;
        }
        ushort4 s0;
        s0.x = f2bf(v0[0]); s0.y = f2bf(v0[1]); s0.z = f2bf(v0[2]); s0.w = f2bf(v0[3]);
        store_a8(apack + (size_t)(t & 1) * PSTR + poff, s0);

        asm volatile("s_waitcnt vmcnt(0)" ::: "memory");   // wave-local store drain
        if (lane == 0)
            __hip_atomic_store(myslot, (unsigned)(t + 1),
                               __ATOMIC_RELAXED, __HIP_MEMORY_SCOPE_AGENT);
        if (qs == 0 && t > 0) ll += logf(on[0]);   // on[0] == c_{t-1}[lane's batch]

        if (t + 1 < LD) {
            // Emission(t+1) while peers publish.
            bf16x8 xb;
            #pragma unroll
            for (int j = 0; j < 8; ++j) {
                const int a = quad * 8 + j;
                const float v = (a < AD)
                    ? inputs[((size_t)b * LD + (t + 1)) * AD + a] : 0.f;
                xb[j] = (short)f2bf(v);
            }
            e = __builtin_amdgcn_mfma_f32_16x16x32_bf16(bmA, xb, fz, 0, 0, 0);

            // Wave-local slot barrier: one coalesced load of the 64 producer slots.
            {
                const unsigned target = (unsigned)(t + 1);
                for (;;) {
                    unsigned v = __hip_atomic_load(pollp, __ATOMIC_RELAXED,
                                                   __HIP_MEMORY_SCOPE_AGENT);
                    if (__ballot(v >= target) == ~0ULL) break;
                    __builtin_amdgcn_s_sleep(1);
                }
            }

            // Consume alpha(t), software-pipelined: pre-issue ALL 64 coalesced loads
            // into a 128-VGPR buffer, then drain with 64 MFMAs (fine-grained vmcnt).
            const unsigned short* cp = apack + (size_t)(t & 1) * PSTR + coff;
            bf16x8 bufr[32];
            #pragma unroll
            for (int kt = 0; kt < 32; ++kt)
                bufr[kt] = load_a16(cp + (size_t)kt * 512);
            acc = fz; on = fz;
            #pragma unroll
            for (int kt = 0; kt < 32; ++kt) {
                acc = __builtin_amdgcn_mfma_f32_16x16x32_bf16(tfr[kt], bufr[kt], acc, 0, 0, 0);
                on  = __builtin_amdgcn_mfma_f32_16x16x32_bf16(ones, bufr[kt], on, 0, 0, 0);
            }
        }
    }

    // Final normalizer c_{L-1}; only qs==0 waves produce output.
    if (qs == 0) {
        for (;;) {
            unsigned v = __hip_atomic_load(pollp, __ATOMIC_RELAXED,
                                           __HIP_MEMORY_SCOPE_AGENT);
            if (__ballot(v >= (unsigned)LD) == ~0ULL) break;
            __builtin_amdgcn_s_sleep(1);
        }
        const unsigned short* cp = apack + (size_t)((LD - 1) & 1) * PSTR + coff;
        bf16x8 bufr[32];
        #pragma unroll
        for (int kt = 0; kt < 32; ++kt)
            bufr[kt] = load_a16(cp + (size_t)kt * 512);
        f32x4 f0 = fz;
        #pragma unroll
        for (int kt = 0; kt < 32; ++kt)
            f0 = __builtin_amdgcn_mfma_f32_16x16x32_bf16(ones, bufr[kt], f0, 0, 0, 0);
        if (mtl == 0 && quad == 0) out[b] = ll + logf(f0[0]);
    }
}

extern "C" void kernel_launch(void* const* d_in, const int* in_sizes, int n_in,
                              void* d_out, int out_size, void* d_ws, size_t ws_size,
                              hipStream_t stream) {
    const float* inputs       = (const float*)d_in[0];
    const float* init_logits  = (const float*)d_in[1];
    const float* trans_logits = (const float*)d_in[2];
    const float* emis_logits  = (const float*)d_in[3];
    float* out = (float*)d_out;

    unsigned short* tf    = (unsigned short*)d_ws;                 // 2 MB
    unsigned short* bmf   = tf + (size_t)QD * QD;                  // 64 KB
    float* pi             = (float*)(bmf + (size_t)QD * 32);       // 4 KB
    unsigned short* apack = (unsigned short*)(pi + QD);            // 512 KB
    unsigned int* slots   = (unsigned int*)(apack + (size_t)2 * PSTR);  // 64 KB

    hipMemsetAsync(slots, 0, (size_t)4 * DOM_SLOTS * SLOT_STRIDE * sizeof(unsigned int),
                   stream);

    softmax_pack_T<<<1024, 256, 0, stream>>>(trans_logits, tf);
    softmax_pack_B<<<4, 256, 0, stream>>>(emis_logits, bmf);
    softmax_pi<<<1, 1024, 0, stream>>>(init_logits, pi);

    void* args[] = {(void*)&inputs, (void*)&tf, (void*)&bmf, (void*)&pi,
                    (void*)&apack, (void*)&slots, (void*)&out};
    hipLaunchCooperativeKernel((const void*)hmm_scan, dim3(NWG), dim3(256),
                               args, 0, stream);
}

// Round 11
// 5891.822 us; speedup vs baseline: 3.0498x; 1.0140x over previous
//
#include <hip/hip_runtime.h>
#include <hip/hip_bf16.h>

#define QD 1024
#define AD 26
#define BD 128
#define LD 1024
#define NWG 128          // 32 q-slices x 4 batch-domains
#define FSTR 32          // uints per WG flag = 128 B line each
#define PSTR (8 * 32 * 64 * 8)   // ushorts per parity of packed alpha (256 KB)

typedef short bf16x8 __attribute__((ext_vector_type(8)));
typedef float f32x4 __attribute__((ext_vector_type(4)));

static __device__ __forceinline__ unsigned short f2bf(float f) {
    __hip_bfloat16 h = __float2bfloat16(f);
    return *reinterpret_cast<unsigned short*>(&h);
}

// Agent-scope relaxed 16B load (two 8B scoped loads -> served from coherence point).
static __device__ __forceinline__ bf16x8 load_a16(const unsigned short* p) {
    unsigned long long lo = __hip_atomic_load((const unsigned long long*)p,
                                              __ATOMIC_RELAXED, __HIP_MEMORY_SCOPE_AGENT);
    unsigned long long hi = __hip_atomic_load((const unsigned long long*)(p + 4),
                                              __ATOMIC_RELAXED, __HIP_MEMORY_SCOPE_AGENT);
    union { unsigned long long q[2]; bf16x8 v; } u;
    u.q[0] = lo; u.q[1] = hi;
    return u.v;
}

// Agent-scope relaxed 8B store (write-through; visible once vmcnt retires).
static __device__ __forceinline__ void store_a8(unsigned short* p, ushort4 v) {
    union { ushort4 s; unsigned long long q; } u; u.s = v;
    __hip_atomic_store((unsigned long long*)p, u.q,
                       __ATOMIC_RELAXED, __HIP_MEMORY_SCOPE_AGENT);
}

// Row-softmax of trans_logits [1024,1024] -> bf16 packed as A-fragments of T^T.
// A-frag layout (16x16x32): A[m = lane&15][k = quad*8 + j].
__global__ void softmax_pack_T(const float* __restrict__ tl, unsigned short* __restrict__ tf) {
    const int i = blockIdx.x;      // q_in
    const int tid = threadIdx.x;   // 256
    __shared__ float red[256];
    float v[4];
    float m = -1e30f;
    for (int c = 0; c < 4; ++c) { v[c] = tl[i * QD + tid + 256 * c]; m = fmaxf(m, v[c]); }
    red[tid] = m; __syncthreads();
    for (int s = 128; s > 0; s >>= 1) { if (tid < s) red[tid] = fmaxf(red[tid], red[tid + s]); __syncthreads(); }
    m = red[0]; __syncthreads();
    float sum = 0.f;
    for (int c = 0; c < 4; ++c) { v[c] = expf(v[c] - m); sum += v[c]; }
    red[tid] = sum; __syncthreads();
    for (int s = 128; s > 0; s >>= 1) { if (tid < s) red[tid] += red[tid + s]; __syncthreads(); }
    const float inv = 1.0f / red[0];
    const int kt = i >> 5, quad = (i >> 3) & 3, j = i & 7;
    for (int c = 0; c < 4; ++c) {
        const int q = tid + 256 * c;
        const int mt = q >> 4, col = q & 15;
        tf[(size_t)((mt * 32 + kt) * 64 + quad * 16 + col) * 8 + j] = f2bf(v[c] * inv);
    }
}

// Row-softmax of emis_logits [1024,26] -> bf16 A-fragments (M=q, K=a padded to 32).
__global__ void softmax_pack_B(const float* __restrict__ el, unsigned short* __restrict__ bmf) {
    const int q = blockIdx.x * blockDim.x + threadIdx.x;
    if (q >= QD) return;
    float v[AD];
    float m = -1e30f;
    for (int a = 0; a < AD; ++a) { v[a] = el[q * AD + a]; m = fmaxf(m, v[a]); }
    float sum = 0.f;
    for (int a = 0; a < AD; ++a) { v[a] = expf(v[a] - m); sum += v[a]; }
    const float inv = 1.0f / sum;
    const int mt = q >> 4, col = q & 15;
    for (int a = 0; a < 32; ++a) {
        const float val = (a < AD) ? v[a] * inv : 0.f;
        bmf[(size_t)(mt * 64 + (a >> 3) * 16 + col) * 8 + (a & 7)] = f2bf(val);
    }
}

__global__ void softmax_pi(const float* __restrict__ il, float* __restrict__ pi) {
    const int tid = threadIdx.x;   // 1024
    __shared__ float red[1024];
    const float v = il[tid];
    red[tid] = v; __syncthreads();
    for (int s = 512; s > 0; s >>= 1) { if (tid < s) red[tid] = fmaxf(red[tid], red[tid + s]); __syncthreads(); }
    const float m = red[0]; __syncthreads();
    const float e = expf(v - m);
    red[tid] = e; __syncthreads();
    for (int s = 512; s > 0; s >>= 1) { if (tid < s) red[tid] += red[tid + s]; __syncthreads(); }
    pi[tid] = e / red[0];
}

// Cooperative scan, 128 WGs x 256 threads = 32 q-slices x 4 independent batch domains.
// R8's proven flag protocol with WG-LEVEL flags: chunk kt is produced jointly by the
// waves of WG (qs=kt, bg), so one flag per WG is the natural granularity. Per step:
// each wave stores its 8B fragment-packed alpha tile -> vmcnt(0) drain ->
// __syncthreads() (all 4 waves drained) -> tid0 publishes flags[bg][qs] = t+1 ->
// consumers poll 32 flag lines (vs 64 per-wave flags in R8) with one coalesced
// wave load + ballot. Overwrite safety: WG flag at t+1 implies all its waves' t+1
// stores drained, each of which data-depends on having finished reading alpha(t).
// Alpha exchange is fragment-packed (producer stores its ushort4 C-values directly
// into the consumer's B-fragment slot; consumer reads each chunk as one coalesced
// 16-B/lane load). T A-frags in registers; consume loop software-pipelined via
// a 32-entry register buffer (all 64 loads in flight before the MFMA drain).
__launch_bounds__(256, 1)
__global__ void hmm_scan(const float* __restrict__ inputs,
                         const unsigned short* __restrict__ tf,
                         const unsigned short* __restrict__ bmf,
                         const float* __restrict__ pi,
                         unsigned short* __restrict__ apack,  // 2 x PSTR ushorts
                         unsigned int* __restrict__ flags,    // [4][32][FSTR] uint, zeroed
                         float* __restrict__ out) {
    const int tid   = threadIdx.x;
    const int wave  = tid >> 6;
    const int lane  = tid & 63;
    const int quad  = lane >> 4;
    const int col   = lane & 15;
    const int mtl   = wave & 1;
    const int bhalf = wave >> 1;
    const int qs    = (int)blockIdx.x >> 2;
    const int bg    = (int)blockIdx.x & 3;
    const int b     = bg * 32 + bhalf * 16 + col;   // this lane's batch
    const int qrow  = qs * 32 + mtl * 16 + quad * 4;
    const int grp   = bg * 2 + bhalf;               // packed group

    unsigned int* dom = flags + (size_t)bg * 32 * FSTR;
    unsigned int* myflag = dom + (size_t)qs * FSTR;
    const unsigned int* pollp = dom + (size_t)(lane & 31) * FSTR;

    // Producer store target (ushort offset within a parity).
    const int lane_c = (mtl * 2 + (quad >> 1)) * 16 + col;
    const size_t poff = (size_t)((grp * 32 + qs) * 64 + lane_c) * 8 + (quad & 1) * 4;
    // Consumer chunk base (ushort offset within a parity); chunk kt at +kt*512.
    const size_t coff = (size_t)(grp * 32) * 512 + (size_t)lane * 8;

    // All 32 T^T A-frags into registers (AGPR side of the unified file).
    bf16x8 tfr[32];
    {
        const bf16x8* tsrc = (const bf16x8*)tf + (size_t)(qs * 2 + mtl) * 32 * 64 + lane;
        #pragma unroll
        for (int kt = 0; kt < 32; ++kt) tfr[kt] = tsrc[(size_t)kt * 64];
    }
    const bf16x8 bmA = *(const bf16x8*)&bmf[(size_t)((qs * 2 + mtl) * 64 + lane) * 8];
    float pr[4];
    #pragma unroll
    for (int r = 0; r < 4; ++r) pr[r] = pi[qrow + r];

    bf16x8 ones;
    #pragma unroll
    for (int i = 0; i < 8; ++i) ones[i] = (short)0x3F80;

    const f32x4 fz = {0.f, 0.f, 0.f, 0.f};
    float ll = 0.f;

    // Emission(0): direct register loads.
    f32x4 e;
    {
        bf16x8 xb;
        #pragma unroll
        for (int j = 0; j < 8; ++j) {
            const int a = quad * 8 + j;
            const float v = (a < AD) ? inputs[(size_t)b * LD * AD + a] : 0.f;
            xb[j] = (short)f2bf(v);
        }
        e = __builtin_amdgcn_mfma_f32_16x16x32_bf16(bmA, xb, fz, 0, 0, 0);
    }

    f32x4 acc = fz, on = fz;

    for (int t = 0; t < LD; ++t) {
        // Hoist next step's emission input loads: they complete during the drain.
        float va[8];
        if (t + 1 < LD) {
            #pragma unroll
            for (int j = 0; j < 8; ++j) {
                const int a = quad * 8 + j;
                va[j] = (a < AD) ? inputs[((size_t)b * LD + (t + 1)) * AD + a] : 0.f;
            }
        }

        float v0[4];
        if (t == 0) {
            #pragma unroll
            for (int r = 0; r < 4; ++r) v0[r] = pr[r] * e[r];
        } else {
            const float i0 = 1.f / on[0];
            #pragma unroll
            for (int r = 0; r < 4; ++r) v0[r] = acc[r] * e[r] * i0;
        }
        ushort4 s0;
        s0.x = f2bf(v0[0]); s0.y = f2bf(v0[1]); s0.z = f2bf(v0[2]); s0.w = f2bf(v0[3]);
        store_a8(apack + (size_t)(t & 1) * PSTR + poff, s0);

        asm volatile("s_waitcnt vmcnt(0)" ::: "memory");   // wave store (+input loads) drain
        __syncthreads();                                   // all 4 waves drained
        if (tid == 0)
            __hip_atomic_store(myflag, (unsigned)(t + 1),
                               __ATOMIC_RELAXED, __HIP_MEMORY_SCOPE_AGENT);
        if (qs == 0 && t > 0) ll += logf(on[0]);   // on[0] == c_{t-1}[lane's batch]

        if (t + 1 < LD) {
            // Emission(t+1) from the pre-loaded inputs while peers publish.
            bf16x8 xb;
            #pragma unroll
            for (int j = 0; j < 8; ++j) xb[j] = (short)f2bf(va[j]);
            e = __builtin_amdgcn_mfma_f32_16x16x32_bf16(bmA, xb, fz, 0, 0, 0);

            // WG-flag barrier: one coalesced load of the domain's 32 flag lines.
            {
                const unsigned target = (unsigned)(t + 1);
                for (;;) {
                    unsigned v = __hip_atomic_load(pollp, __ATOMIC_RELAXED,
                                                   __HIP_MEMORY_SCOPE_AGENT);
                    if (__ballot(v >= target) == ~0ULL) break;
                    __builtin_amdgcn_s_sleep(1);
                }
            }

            // Consume alpha(t), software-pipelined: pre-issue ALL 64 coalesced loads
            // into a 128-VGPR buffer, then drain with 64 MFMAs (fine-grained vmcnt).
            const unsigned short* cp = apack + (size_t)(t & 1) * PSTR + coff;
            bf16x8 bufr[32];
            #pragma unroll
            for (int kt = 0; kt < 32; ++kt)
                bufr[kt] = load_a16(cp + (size_t)kt * 512);
            acc = fz; on = fz;
            #pragma unroll
            for (int kt = 0; kt < 32; ++kt) {
                acc = __builtin_amdgcn_mfma_f32_16x16x32_bf16(tfr[kt], bufr[kt], acc, 0, 0, 0);
                on  = __builtin_amdgcn_mfma_f32_16x16x32_bf16(ones, bufr[kt], on, 0, 0, 0);
            }
        }
    }

    // Final normalizer c_{L-1}; only qs==0 waves produce output.
    if (qs == 0) {
        for (;;) {
            unsigned v = __hip_atomic_load(pollp, __ATOMIC_RELAXED,
                                           __HIP_MEMORY_SCOPE_AGENT);
            if (__ballot(v >= (unsigned)LD) == ~0ULL) break;
            __builtin_amdgcn_s_sleep(1);
        }
        const unsigned short* cp = apack + (size_t)((LD - 1) & 1) * PSTR + coff;
        bf16x8 bufr[32];
        #pragma unroll
        for (int kt = 0; kt < 32; ++kt)
            bufr[kt] = load_a16(cp + (size_t)kt * 512);
        f32x4 f0 = fz;
        #pragma unroll
        for (int kt = 0; kt < 32; ++kt)
            f0 = __builtin_amdgcn_mfma_f32_16x16x32_bf16(ones, bufr[kt], f0, 0, 0, 0);
        if (mtl == 0 && quad == 0) out[b] = ll + logf(f0[0]);
    }
}

extern "C" void kernel_launch(void* const* d_in, const int* in_sizes, int n_in,
                              void* d_out, int out_size, void* d_ws, size_t ws_size,
                              hipStream_t stream) {
    const float* inputs       = (const float*)d_in[0];
    const float* init_logits  = (const float*)d_in[1];
    const float* trans_logits = (const float*)d_in[2];
    const float* emis_logits  = (const float*)d_in[3];
    float* out = (float*)d_out;

    unsigned short* tf    = (unsigned short*)d_ws;                 // 2 MB
    unsigned short* bmf   = tf + (size_t)QD * QD;                  // 64 KB
    float* pi             = (float*)(bmf + (size_t)QD * 32);       // 4 KB
    unsigned short* apack = (unsigned short*)(pi + QD);            // 512 KB
    unsigned int* flagsb  = (unsigned int*)(apack + (size_t)2 * PSTR);  // 16 KB

    hipMemsetAsync(flagsb, 0, (size_t)4 * 32 * FSTR * sizeof(unsigned int), stream);

    softmax_pack_T<<<1024, 256, 0, stream>>>(trans_logits, tf);
    softmax_pack_B<<<4, 256, 0, stream>>>(emis_logits, bmf);
    softmax_pi<<<1, 1024, 0, stream>>>(init_logits, pi);

    void* args[] = {(void*)&inputs, (void*)&tf, (void*)&bmf, (void*)&pi,
                    (void*)&apack, (void*)&flagsb, (void*)&out};
    hipLaunchCooperativeKernel((const void*)hmm_scan, dim3(NWG), dim3(256),
                               args, 0, stream);
}